// Round 2
// 646.386 us; speedup vs baseline: 1.0482x; 1.0482x over previous
//
#include <hip/hip_runtime.h>
#include <math.h>

#define BB 2
#define CC 192
#define SS 512
#define BW 21
#define HALF 10
#define KS 7
#define PITCH 21  // LDS pitch for P; odd => stride-21 reads hit all 32 banks (2-way max, free)

typedef float fvec4 __attribute__((ext_vector_type(4)));  // native vector: OK for nontemporal builtins

// Kernel 1: band mean over vertical 21-window at the diagonal column, then
// depthwise conv1d k=7 (cross-correlation, zero pad 3). One block per (b,c).
//
// Coalesced restage: for row r the needed columns r-10..r+10 are CONTIGUOUS in
// memory. Stage P[r][i] = x[r][r+i-10] via row-segment reads (2 cache lines per
// row instead of 21 scattered lines), then band[j] = sum_k P[j-10+k][20-k] from
// LDS. Old version: lane stride 513 floats => 64 lines per load instruction.
__global__ __launch_bounds__(SS) void band_conv_kernel(
    const float* __restrict__ x, const float* __restrict__ conv_w,
    float* __restrict__ attn1) {
  const int bc = blockIdx.x;            // b*CC + c
  const int c  = bc % CC;
  const int j  = threadIdx.x;           // column / diag position, 0..511
  const float* xs = x + (size_t)bc * SS * SS;

  __shared__ float P[SS][PITCH];        // P[r][i] = x[r][r+i-10] (0 if col OOB)
  __shared__ float sband[SS + 2 * (KS / 2)];  // band with 3-wide zero halo

  // Stage: 16 groups of 32 lanes; group g loads row r = it*16 + g as one
  // contiguous 21-float segment (lanes 0..20 active).
  const int lane32 = j & 31;
  const int grp    = j >> 5;            // 0..15
#pragma unroll 4
  for (int it = 0; it < SS / 16; ++it) {
    const int r = it * 16 + grp;
    if (lane32 < BW) {
      const int col = r + lane32 - HALF;
      float v = 0.f;
      if (col >= 0 && col < SS) v = xs[(size_t)r * SS + col];
      P[r][lane32] = v;
    }
  }
  if (j < KS / 2) {                     // zero conv halo
    sband[j] = 0.f;
    sband[SS + KS / 2 + j] = 0.f;
  }
  __syncthreads();

  // band[j] = (1/21) * sum_{k} P[j-10+k][20-k]  (row OOB => 0, matches zero row-pad)
  // LDS read stride across lanes = PITCH = 21 words (odd) => conflict-free.
  float s = 0.f;
#pragma unroll
  for (int k = 0; k < BW; ++k) {
    const int r = j - HALF + k;
    if (r >= 0 && r < SS) s += P[r][BW - 1 - k];
  }
  sband[KS / 2 + j] = s * (1.0f / (float)BW);
  __syncthreads();

  float w[KS];
#pragma unroll
  for (int t = 0; t < KS; ++t) w[t] = conv_w[c * KS + t];

  float acc = 0.f;
#pragma unroll
  for (int t = 0; t < KS; ++t) acc += sband[j + t] * w[t];  // halo => no bounds check
  attn1[(size_t)bc * SS + j] = acc;
}

// Kernel 2: pointwise [C x C] mix + bias, then softmax over s per (b,d).
// One block per (b,d), 512 threads = 8 waves. attn1 slice (384 KB) is L2-hot.
__global__ __launch_bounds__(SS) void point_softmax_kernel(
    const float* __restrict__ attn1, const float* __restrict__ point_w,
    const float* __restrict__ point_b, float* __restrict__ attn2) {
  const int bd = blockIdx.x;            // b*CC + d
  const int b  = bd / CC;
  const int d  = bd % CC;
  const int s  = threadIdx.x;

  const float* a1 = attn1 + (size_t)b * CC * SS;
  const float* pw = point_w + (size_t)d * CC;   // block-uniform -> s_loads

  float acc = point_b[d];
#pragma unroll 4
  for (int c = 0; c < CC; ++c) acc += pw[c] * a1[(size_t)c * SS + s];

  // block softmax over the 512 s-values
  const int wave = s >> 6, lane = s & 63;
  __shared__ float redm[8];
  __shared__ float reds[8];

  float m = acc;
#pragma unroll
  for (int off = 32; off >= 1; off >>= 1) m = fmaxf(m, __shfl_xor(m, off, 64));
  if (lane == 0) redm[wave] = m;
  __syncthreads();
  float bm = redm[0];
#pragma unroll
  for (int i = 1; i < 8; ++i) bm = fmaxf(bm, redm[i]);

  float e = expf(acc - bm);
  float ss = e;
#pragma unroll
  for (int off = 32; off >= 1; off >>= 1) ss += __shfl_xor(ss, off, 64);
  if (lane == 0) reds[wave] = ss;
  __syncthreads();
  float bs = 0.f;
#pragma unroll
  for (int i = 0; i < 8; ++i) bs += reds[i];

  attn2[(size_t)bd * SS + s] = e / bs;
}

// Kernel 3: out = x, with the main diagonal scaled by attn2. float4 streaming
// copy with nontemporal hints (805 MB r+w, BW-bound). attn2 read stays cached.
__global__ __launch_bounds__(256) void diag_scale_copy_kernel(
    const fvec4* __restrict__ xin, const float* __restrict__ attn2,
    fvec4* __restrict__ out) {
  const size_t v = (size_t)blockIdx.x * blockDim.x + threadIdx.x;  // float4 idx
  const size_t e = v << 2;                                         // element idx
  fvec4 val = __builtin_nontemporal_load(&xin[v]);
  const int row     = (int)((e >> 9) & (SS - 1));
  const int colbase = (int)(e & (SS - 1));
  if ((row >> 2) == (colbase >> 2)) {
    const int slab = (int)(e >> 18);               // b*CC + c
    const float a = attn2[(size_t)slab * SS + row];
    val[row & 3] *= a;
  }
  __builtin_nontemporal_store(val, &out[v]);
}

extern "C" void kernel_launch(void* const* d_in, const int* in_sizes, int n_in,
                              void* d_out, int out_size, void* d_ws, size_t ws_size,
                              hipStream_t stream) {
  const float* x       = (const float*)d_in[0];
  const float* conv_w  = (const float*)d_in[1];
  const float* point_w = (const float*)d_in[2];
  const float* point_b = (const float*)d_in[3];
  float* out = (float*)d_out;

  float* attn1 = (float*)d_ws;                       // B*C*S floats = 768 KB
  float* attn2 = attn1 + (size_t)BB * CC * SS;       // another 768 KB

  band_conv_kernel<<<BB * CC, SS, 0, stream>>>(x, conv_w, attn1);
  point_softmax_kernel<<<BB * CC, SS, 0, stream>>>(attn1, point_w, point_b, attn2);

  const size_t total4 = (size_t)BB * CC * SS * SS / 4;   // 25165824
  const int blk = 256;
  const int grid = (int)(total4 / blk);                  // 98304, exact
  diag_scale_copy_kernel<<<grid, blk, 0, stream>>>((const fvec4*)x, attn2,
                                                   (fvec4*)out);
}